// Round 4
// baseline (806.549 us; speedup 1.0000x reference)
//
#include <hip/hip_runtime.h>
#include <math.h>

// VanillaRNN via MFMA: B=1024, T=512, I=64, H=128, O=10, fp32 in/out.
// R11: barrier-free single-wave chain, built ONLY from field-verified pieces.
//  - R9/R10 (transposed recurrence + VOP3P pk-asm) failed with O(1) absmax
//    even after the write->read fence => bug lives in the never-verified
//    transposed maps / packed-asm path. Abandoned.
//  - This round keeps the structural win (no s_barrier: one wave owns a
//    whole 16-batch chain, so the h handoff is a same-wave LDS round trip)
//    but reuses the R7/R8-verified orientation verbatim:
//      A = h fragment  hbuf[c*PITCH + kt*32 + 8q]          (R7/R8 verified)
//      B = weight cols, paired n0=32np+2c / n0+1           (R8 verified)
//      D write = pk2(h0,h1) b32 at [m=4q+r][n0]            (R8 verified)
//      tanh = exp2-based, 2 trans ops                      (R7 verified)
//      x as A-operand via pk2 pack, depth-2 prefetch       (R7 verified)
//  - One wave does everything: 48 MFMAs/step (16 x-part + 32 h-part),
//    32 tanh/lane. All of W_hh/W_hx pinned as B-frags (48 int4 = 192 VGPR).
//  - Same-wave write->read hop fenced by s_waitcnt lgkmcnt(0) + "memory"
//    clobber + sched_barrier(0) (rule #18). WAR closed by register dataflow.
//  - 64 blocks x 64 threads; waves_per_eu(1,1) for the 512-VGPR budget.

#define T_STEPS 512
#define I_DIM   64
#define H_DIM   128
#define O_DIM   10
#define BT      16            // batch rows per block (= per chain)
#define PITCH   136           // bf16 per hbuf row (R8-verified, 2-way banks)

typedef short  bf16x8 __attribute__((ext_vector_type(8)));
typedef float  f32x4  __attribute__((ext_vector_type(4)));

#define MFMA(A, Bi, C) __builtin_amdgcn_mfma_f32_16x16x32_bf16(                 \
    __builtin_bit_cast(bf16x8, (A)), __builtin_bit_cast(bf16x8, (Bi)), (C), 0, 0, 0)

static __device__ inline short f2bf(float f) {               // full RNE (preload only)
    union { float f; unsigned u; } v; v.f = f;
    unsigned r = v.u + 0x7FFFu + ((v.u >> 16) & 1u);
    return (short)(r >> 16);
}
static __device__ inline int pk2(float a, float b) {         // fast packed round (R7)
    unsigned ua = __builtin_bit_cast(unsigned, a);
    unsigned ub = __builtin_bit_cast(unsigned, b);
    return (int)(((ua + 0x8000u) >> 16) | ((ub + 0x8000u) & 0xFFFF0000u));
}
static __device__ inline float bf2f(short s) {
    union { unsigned u; float f; } v; v.u = ((unsigned)(unsigned short)s) << 16;
    return v.f;
}
static __device__ inline float tanh_fast(float z) {          // R7-verified exp2 form
    float e = __builtin_amdgcn_exp2f(z * 2.885390081777926825f);
    return fmaf(-2.0f, __builtin_amdgcn_rcpf(e + 1.0f), 1.0f);
}
static __device__ inline int4 load_frag(const float* src) {  // f32 row -> bf16x8 frag
    short e[8];
    #pragma unroll
    for (int j = 0; j < 8; ++j) e[j] = f2bf(src[j]);
    int4 r;
    r.x = ((int)(unsigned short)e[0]) | ((int)(unsigned short)e[1] << 16);
    r.y = ((int)(unsigned short)e[2]) | ((int)(unsigned short)e[3] << 16);
    r.z = ((int)(unsigned short)e[4]) | ((int)(unsigned short)e[5] << 16);
    r.w = ((int)(unsigned short)e[6]) | ((int)(unsigned short)e[7] << 16);
    return r;
}
// Same-wave LDS write->read fence: compiler memory barrier + HW drain + no
// instruction motion across (rule #18).
static __device__ inline void lds_fence() {
    asm volatile("s_waitcnt lgkmcnt(0)" ::: "memory");
    __builtin_amdgcn_sched_barrier(0);
}

// One timestep: read h_t frags, 48 MFMAs, tanh, write h_{t+1}, fence,
// prep next step's x A-frags from XR, reload XR <- x_TN.
#define RNN_STEP(XR, TN)                                                        \
    {                                                                           \
        const short* hb = hbuf + c * PITCH + q * 8;                             \
        bf16x8 Ah0 = *(const bf16x8*)(hb +  0);                                 \
        bf16x8 Ah1 = *(const bf16x8*)(hb + 32);                                 \
        bf16x8 Ah2 = *(const bf16x8*)(hb + 64);                                 \
        bf16x8 Ah3 = *(const bf16x8*)(hb + 96);                                 \
        f32x4 C[4][2];                                                          \
        _Pragma("unroll")                                                       \
        for (int np = 0; np < 4; ++np) {                                        \
            _Pragma("unroll")                                                   \
            for (int sub = 0; sub < 2; ++sub) {                                 \
                C[np][sub] = MFMA(AXF[0], BW[np][sub][4], biasC4[np][sub]);     \
                C[np][sub] = MFMA(AXF[1], BW[np][sub][5], C[np][sub]);          \
                C[np][sub] = MFMA(Ah0, BW[np][sub][0], C[np][sub]);             \
                C[np][sub] = MFMA(Ah1, BW[np][sub][1], C[np][sub]);             \
                C[np][sub] = MFMA(Ah2, BW[np][sub][2], C[np][sub]);             \
                C[np][sub] = MFMA(Ah3, BW[np][sub][3], C[np][sub]);             \
            }                                                                   \
        }                                                                       \
        _Pragma("unroll")                                                       \
        for (int np = 0; np < 4; ++np) {                                        \
            _Pragma("unroll")                                                   \
            for (int r = 0; r < 4; ++r) {                                       \
                const int m = q * 4 + r;                                        \
                const float h0 = tanh_fast(C[np][0][r]);                        \
                const float h1 = tanh_fast(C[np][1][r]);                        \
                *(int*)(hbuf + m * PITCH + 32 * np + 2 * c) = pk2(h0, h1);      \
            }                                                                   \
        }                                                                       \
        lds_fence();                                                            \
        AXF[0] = pack4(XR[0], XR[1]);                                           \
        AXF[1] = pack4(XR[2], XR[3]);                                           \
        {                                                                       \
            const int tn = ((TN) < T_STEPS) ? (TN) : (T_STEPS - 1);             \
            const float* pn = xrow + (size_t)tn * I_DIM;                        \
            XR[0] = *(const float4*)(pn +      q * 8);                          \
            XR[1] = *(const float4*)(pn +      q * 8 + 4);                      \
            XR[2] = *(const float4*)(pn + 32 + q * 8);                          \
            XR[3] = *(const float4*)(pn + 32 + q * 8 + 4);                      \
        }                                                                       \
    }

static __device__ inline int4 pack4(const float4 a, const float4 b) {  // R7 pk2 pack
    int4 r;
    r.x = pk2(a.x, a.y); r.y = pk2(a.z, a.w);
    r.z = pk2(b.x, b.y); r.w = pk2(b.z, b.w);
    return r;
}

__global__ __launch_bounds__(64, 1)
__attribute__((amdgpu_waves_per_eu(1, 1)))
void rnn_mfma_kernel(
    const float* __restrict__ x,      // [B, T, I]
    const float* __restrict__ W_hx,   // [H, I]
    const float* __restrict__ W_hh,   // [H, H]
    const float* __restrict__ b_hh,   // [H]
    const float* __restrict__ W_ph,   // [O, H]
    const float* __restrict__ b_ph,   // [O]
    float* __restrict__ out)          // [B, O]
{
    const int b0   = blockIdx.x * BT;
    const int tid  = threadIdx.x;
    const int lane = tid & 63;
    const int c    = lane & 15;       // A row = batch; B col pair base
    const int q    = lane >> 4;       // k-slice / C row group

    __shared__ __align__(16) short hbuf[BT * PITCH];   // h [batch][hidden] bf16

    // ---- Pinned B-operand weights, paired columns (R8-verified trick):
    // BW[np][sub][kt]: lane holds column n = 32*np + 2*c + sub,
    //   kt 0..3 -> W_hh[n][kt*32 + 8q..+7], kt 4..5 -> W_hx[n][(kt-4)*32 + 8q..+7]
    int4 BW[4][2][6];
    f32x4 biasC4[4][2];               // splat(b_hh[n]) as C seed
    #pragma unroll
    for (int np = 0; np < 4; ++np) {
        #pragma unroll
        for (int sub = 0; sub < 2; ++sub) {
            const int n = 32 * np + 2 * c + sub;
            #pragma unroll
            for (int kt = 0; kt < 6; ++kt) {
                const float* src = (kt < 4) ? (W_hh + n * H_DIM + kt * 32 + q * 8)
                                            : (W_hx + n * I_DIM + (kt - 4) * 32 + q * 8);
                BW[np][sub][kt] = load_frag(src);
            }
            const float bb = b_hh[n];
            biasC4[np][sub] = (f32x4){bb, bb, bb, bb};
        }
    }
    #pragma unroll
    for (int np = 0; np < 4; ++np)
        #pragma unroll
        for (int sub = 0; sub < 2; ++sub) {
            #pragma unroll
            for (int kt = 0; kt < 6; ++kt)
                asm volatile("" : "+v"(BW[np][sub][kt].x), "+v"(BW[np][sub][kt].y),
                                  "+v"(BW[np][sub][kt].z), "+v"(BW[np][sub][kt].w));
            asm volatile("" : "+v"(biasC4[np][sub]));
        }

    // ---- h_0 = 0 in LDS (A-frags are read from LDS every step).
    for (int idx = tid; idx < BT * PITCH; idx += 64) hbuf[idx] = 0;
    lds_fence();   // init writes -> first step's reads (no dataflow link)

    // ---- x pipeline (R7-verified): AXF = x^A frags of CURRENT step,
    // depth-2 raw prefetch in xrA/xrB.
    const float* xrow = x + (size_t)(b0 + c) * T_STEPS * I_DIM;
    int4 AXF[2];
    {
        float4 x0[4];
        x0[0] = *(const float4*)(xrow +      q * 8);
        x0[1] = *(const float4*)(xrow +      q * 8 + 4);
        x0[2] = *(const float4*)(xrow + 32 + q * 8);
        x0[3] = *(const float4*)(xrow + 32 + q * 8 + 4);
        AXF[0] = pack4(x0[0], x0[1]);
        AXF[1] = pack4(x0[2], x0[3]);
    }
    float4 xrA[4], xrB[4];
    {
        const float* p1 = xrow + I_DIM;
        xrA[0] = *(const float4*)(p1 +      q * 8);
        xrA[1] = *(const float4*)(p1 +      q * 8 + 4);
        xrA[2] = *(const float4*)(p1 + 32 + q * 8);
        xrA[3] = *(const float4*)(p1 + 32 + q * 8 + 4);
        const float* p2 = xrow + 2 * I_DIM;
        xrB[0] = *(const float4*)(p2 +      q * 8);
        xrB[1] = *(const float4*)(p2 +      q * 8 + 4);
        xrB[2] = *(const float4*)(p2 + 32 + q * 8);
        xrB[3] = *(const float4*)(p2 + 32 + q * 8 + 4);
    }

    #pragma unroll 1
    for (int t = 0; t < T_STEPS; t += 2) {
        RNN_STEP(xrA, t + 3)   // step t:   AXF = x_t;   preps AXF(x_{t+1}), xrA <- x_{t+3}
        RNN_STEP(xrB, t + 4)   // step t+1: AXF = x_{t+1}; preps AXF(x_{t+2}), xrB <- x_{t+4}
    }

    // ---- Epilogue: h_512 in hbuf[batch][hidden] (drained by last fence).
    for (int idx = tid; idx < BT * O_DIM; idx += 64) {
        const int m = idx / O_DIM;
        const int o = idx % O_DIM;
        float acc = b_ph[o];
        #pragma unroll 4
        for (int k = 0; k < H_DIM; ++k)
            acc = fmaf(W_ph[o * H_DIM + k], bf2f(hbuf[m * PITCH + k]), acc);
        out[(size_t)(b0 + m) * O_DIM + o] = acc;
    }
}

extern "C" void kernel_launch(void* const* d_in, const int* in_sizes, int n_in,
                              void* d_out, int out_size, void* d_ws, size_t ws_size,
                              hipStream_t stream) {
    const float* x    = (const float*)d_in[0];
    const float* W_hx = (const float*)d_in[1];
    const float* W_hh = (const float*)d_in[2];
    const float* b_hh = (const float*)d_in[3];
    const float* W_ph = (const float*)d_in[4];
    const float* b_ph = (const float*)d_in[5];
    float* out = (float*)d_out;

    rnn_mfma_kernel<<<1024 / BT, 64, 0, stream>>>(x, W_hx, W_hh, b_hh, W_ph, b_ph, out);
}

// Round 5
// 657.483 us; speedup vs baseline: 1.2267x; 1.2267x over previous
//
#include <hip/hip_runtime.h>
#include <math.h>

// VanillaRNN via MFMA: B=1024, T=512, I=64, H=128, O=10, fp32 in/out.
// R12: DUAL-CHAIN interleave. R11 post-mortem: (a) 224 pinned VGPRs spilled
// (168 reported < pinned set; 256-addressable cap), (b) trans ops measured
// ~16-24 cyc/wave64 (R11's one SIMD = 51% VALU-busy = 1609 cyc/step), so
// 32 tanh/lane on one SIMD can never win. Back to the R8-verified 4-wave
// consumer, but the per-step SIMD idle (~500-1100 cyc in R7/R8) is filled
// with a SECOND independent chain:
//  - 32 blocks x 512 threads. Waves 0-3 = chain A (batch b0..b0+15),
//    waves 4-7 = chain B (b0+16..b0+31). Each SIMD hosts one A-wave + one
//    B-wave; when one stalls (ds latency, barrier, MFMA chain) the other
//    issues. Common lds_barrier per step (R8-verified mechanism, 8 waves).
//  - Each wave is self-contained (R7-style): x-part MFMAs + x pk2-convert
//    in the previous step's tail, seeded with bias (R8 producer pattern);
//    h-part 8 MFMAs seeded from the x accumulators (R7 pattern).
//  - Paired-column B-frags n0=32w+2c (R8): tanh pair packs into one b32 LDS
//    write. tanh = Pade[3/3] (R8-verified) + NEW shared-rcp per pair:
//    r=rcp(q0*q1); 1/q0=r*q1 (exact to rcp precision; q>0 always).
//  - Depth-2 raw-x prefetch, LDS-only barrier (no vmcnt drain): R7-verified.

#define T_STEPS 512
#define I_DIM   64
#define H_DIM   128
#define O_DIM   10
#define BT      16            // batch rows per chain
#define NCH     2             // chains per block
#define PITCH   136           // bf16 elements per h row

typedef short  bf16x8 __attribute__((ext_vector_type(8)));
typedef float  f32x4  __attribute__((ext_vector_type(4)));

#define MFMA(A, Bi, C) __builtin_amdgcn_mfma_f32_16x16x32_bf16(                 \
    __builtin_bit_cast(bf16x8, (A)), __builtin_bit_cast(bf16x8, (Bi)), (C), 0, 0, 0)

static __device__ inline short f2bf(float f) {               // full RNE (preload only)
    union { float f; unsigned u; } v; v.f = f;
    unsigned r = v.u + 0x7FFFu + ((v.u >> 16) & 1u);
    return (short)(r >> 16);
}
static __device__ inline int pk2(float a, float b) {         // fast packed round
    unsigned ua = __builtin_bit_cast(unsigned, a);
    unsigned ub = __builtin_bit_cast(unsigned, b);
    return (int)(((ua + 0x8000u) >> 16) | ((ub + 0x8000u) & 0xFFFF0000u));
}
static __device__ inline float bf2f(short s) {
    union { unsigned u; float f; } v; v.u = ((unsigned)(unsigned short)s) << 16;
    return v.f;
}
static __device__ inline int4 load_frag(const float* src) {  // f32 row -> bf16x8 frag
    short e[8];
    #pragma unroll
    for (int j = 0; j < 8; ++j) e[j] = f2bf(src[j]);
    int4 r;
    r.x = ((int)(unsigned short)e[0]) | ((int)(unsigned short)e[1] << 16);
    r.y = ((int)(unsigned short)e[2]) | ((int)(unsigned short)e[3] << 16);
    r.z = ((int)(unsigned short)e[4]) | ((int)(unsigned short)e[5] << 16);
    r.w = ((int)(unsigned short)e[6]) | ((int)(unsigned short)e[7] << 16);
    return r;
}
static __device__ inline int4 pack4(const float4 a, const float4 b) {  // x A-frag pack
    int4 r;
    r.x = pk2(a.x, a.y); r.y = pk2(a.z, a.w);
    r.z = pk2(b.x, b.y); r.w = pk2(b.z, b.w);
    return r;
}
// Barrier that does NOT drain vmcnt: h handoff only needs LDS ops complete.
static __device__ inline void lds_barrier() {
    asm volatile("s_waitcnt lgkmcnt(0)\n\ts_barrier" ::: "memory");
}

// One step for one wave of one chain. Entry: Cx0/Cx1 hold x-part+bias of
// THIS step (cols n0, n0+1). Body: h-MFMAs, tanh pair (shared rcp), b32
// write. Tail: pack next x, compute next Cx, reload XR <- x_TN.
#define RNN_STEP(P, XR, TN)                                                     \
    {                                                                           \
        const short* hb = hsrc[P] + c * PITCH + q * 8;                          \
        bf16x8 Ah0 = *(const bf16x8*)(hb +  0);                                 \
        bf16x8 Ah1 = *(const bf16x8*)(hb + 32);                                 \
        bf16x8 Ah2 = *(const bf16x8*)(hb + 64);                                 \
        bf16x8 Ah3 = *(const bf16x8*)(hb + 96);                                 \
        f32x4 Ca0 = Cx0, Ca1 = Cx1;                                             \
        f32x4 Cb0 = {0.f, 0.f, 0.f, 0.f};                                       \
        f32x4 Cb1 = {0.f, 0.f, 0.f, 0.f};                                       \
        Ca0 = MFMA(Ah0, BW[0][0], Ca0); Ca1 = MFMA(Ah0, BW[1][0], Ca1);         \
        Cb0 = MFMA(Ah1, BW[0][1], Cb0); Cb1 = MFMA(Ah1, BW[1][1], Cb1);         \
        Ca0 = MFMA(Ah2, BW[0][2], Ca0); Ca1 = MFMA(Ah2, BW[1][2], Ca1);         \
        Cb0 = MFMA(Ah3, BW[0][3], Cb0); Cb1 = MFMA(Ah3, BW[1][3], Cb1);         \
        const f32x4 C0 = Ca0 + Cb0;                                             \
        const f32x4 C1 = Ca1 + Cb1;                                             \
        short* hw = hsrc[1 - (P)];                                              \
        _Pragma("unroll")                                                       \
        for (int r = 0; r < 4; ++r) {                                           \
            const int m = q * 4 + r;                                            \
            const float z0 = C0[r], z1 = C1[r];                                 \
            const float t0 = z0 * z0, t1 = z1 * z1;                             \
            const float p0 = fmaf(fmaf(t0 + 378.f, t0, 17325.f), t0, 135135.f); \
            const float p1 = fmaf(fmaf(t1 + 378.f, t1, 17325.f), t1, 135135.f); \
            const float q0 = fmaf(fmaf(fmaf(28.f, t0, 3150.f), t0, 62370.f), t0, 135135.f); \
            const float q1 = fmaf(fmaf(fmaf(28.f, t1, 3150.f), t1, 62370.f), t1, 135135.f); \
            const float rr = __builtin_amdgcn_rcpf(q0 * q1);                    \
            const float h0 = __builtin_amdgcn_fmed3f(z0 * p0 * (rr * q1), -1.f, 1.f); \
            const float h1 = __builtin_amdgcn_fmed3f(z1 * p1 * (rr * q0), -1.f, 1.f); \
            *(int*)(hw + m * PITCH + n0) = pk2(h0, h1);                         \
        }                                                                       \
        /* ---- tail: x-part of the NEXT step (independent of h) */             \
        {                                                                       \
            int4 ax0, ax1;                                                      \
            ax0.x = pk2(XR[0].x, XR[0].y); ax0.y = pk2(XR[0].z, XR[0].w);       \
            ax0.z = pk2(XR[1].x, XR[1].y); ax0.w = pk2(XR[1].z, XR[1].w);       \
            ax1.x = pk2(XR[2].x, XR[2].y); ax1.y = pk2(XR[2].z, XR[2].w);       \
            ax1.z = pk2(XR[3].x, XR[3].y); ax1.w = pk2(XR[3].z, XR[3].w);       \
            const int tn = ((TN) < T_STEPS) ? (TN) : (T_STEPS - 1);             \
            const float* pn = xrow + (size_t)tn * I_DIM;                        \
            XR[0] = *(const float4*)(pn +      q * 8);                          \
            XR[1] = *(const float4*)(pn +      q * 8 + 4);                      \
            XR[2] = *(const float4*)(pn + 32 + q * 8);                          \
            XR[3] = *(const float4*)(pn + 32 + q * 8 + 4);                      \
            Cx0 = MFMA(ax0, BW[0][4], biasv[0]);                                \
            Cx0 = MFMA(ax1, BW[0][5], Cx0);                                     \
            Cx1 = MFMA(ax0, BW[1][4], biasv[1]);                                \
            Cx1 = MFMA(ax1, BW[1][5], Cx1);                                     \
        }                                                                       \
        lds_barrier();                                                          \
    }

__global__ __launch_bounds__(512, 2)
void rnn_mfma_kernel(
    const float* __restrict__ x,      // [B, T, I]
    const float* __restrict__ W_hx,   // [H, I]
    const float* __restrict__ W_hh,   // [H, H]
    const float* __restrict__ b_hh,   // [H]
    const float* __restrict__ W_ph,   // [O, H]
    const float* __restrict__ b_ph,   // [O]
    float* __restrict__ out)          // [B, O]
{
    const int tid  = threadIdx.x;
    const int wave = tid >> 6;
    const int g    = wave >> 2;       // chain group 0/1
    const int w    = wave & 3;        // N-slice [32w, 32w+32)
    const int lane = tid & 63;
    const int c    = lane & 15;
    const int q    = lane >> 4;
    const int n0   = w * 32 + 2 * c;  // paired columns n0, n0+1
    const int b0   = blockIdx.x * (BT * NCH) + g * BT;   // chain batch base

    __shared__ __align__(16) short hbuf[NCH][2][BT * PITCH];   // per-chain ping-pong
    short* hsrc[2] = { hbuf[g][0], hbuf[g][1] };

    // ---- Pinned B-operand weights, paired columns (R8-verified):
    // BW[sub][kt]: col n = n0+sub; kt 0..3 = W_hh k-tiles, 4..5 = W_hx k-tiles.
    int4 BW[2][6];
    f32x4 biasv[2];
    #pragma unroll
    for (int sub = 0; sub < 2; ++sub) {
        const int n = n0 + sub;
        #pragma unroll
        for (int kt = 0; kt < 6; ++kt) {
            const float* src = (kt < 4) ? (W_hh + n * H_DIM + kt * 32 + q * 8)
                                        : (W_hx + n * I_DIM + (kt - 4) * 32 + q * 8);
            BW[sub][kt] = load_frag(src);
        }
        const float bb = b_hh[n];
        biasv[sub] = (f32x4){bb, bb, bb, bb};
    }
    #pragma unroll
    for (int sub = 0; sub < 2; ++sub) {
        #pragma unroll
        for (int kt = 0; kt < 6; ++kt)
            asm volatile("" : "+v"(BW[sub][kt].x), "+v"(BW[sub][kt].y),
                              "+v"(BW[sub][kt].z), "+v"(BW[sub][kt].w));
        asm volatile("" : "+v"(biasv[sub]));
    }

    // ---- h0 = 0 (both chains)
    for (int idx = tid; idx < NCH * BT * PITCH; idx += 512)
        hbuf[0][0][idx % (BT * PITCH) + (idx / (BT * PITCH)) * 0] = 0;  // see below
    // (simpler + correct: zero the whole first ping-pong planes)
    for (int idx = tid; idx < NCH * 2 * BT * PITCH; idx += 512)
        ((short*)hbuf)[idx] = 0;

    // ---- Depth-2 raw-x prefetch: xrA <- x_0, xrB <- x_1.
    const float* xrow = x + (size_t)(b0 + c) * T_STEPS * I_DIM;
    float4 xrA[4], xrB[4];
    {
        const float* p0 = xrow;
        xrA[0] = *(const float4*)(p0 +      q * 8);
        xrA[1] = *(const float4*)(p0 +      q * 8 + 4);
        xrA[2] = *(const float4*)(p0 + 32 + q * 8);
        xrA[3] = *(const float4*)(p0 + 32 + q * 8 + 4);
        const float* p1 = xrow + I_DIM;
        xrB[0] = *(const float4*)(p1 +      q * 8);
        xrB[1] = *(const float4*)(p1 +      q * 8 + 4);
        xrB[2] = *(const float4*)(p1 + 32 + q * 8);
        xrB[3] = *(const float4*)(p1 + 32 + q * 8 + 4);
    }

    // ---- Pre-loop: Cx for step 0 from xrA (= x_0); reissue xrA <- x_2.
    f32x4 Cx0, Cx1;
    {
        int4 ax0, ax1;
        ax0 = pack4(xrA[0], xrA[1]);
        ax1 = pack4(xrA[2], xrA[3]);
        const float* p2 = xrow + 2 * I_DIM;
        xrA[0] = *(const float4*)(p2 +      q * 8);
        xrA[1] = *(const float4*)(p2 +      q * 8 + 4);
        xrA[2] = *(const float4*)(p2 + 32 + q * 8);
        xrA[3] = *(const float4*)(p2 + 32 + q * 8 + 4);
        Cx0 = MFMA(ax0, BW[0][4], biasv[0]);
        Cx0 = MFMA(ax1, BW[0][5], Cx0);
        Cx1 = MFMA(ax0, BW[1][4], biasv[1]);
        Cx1 = MFMA(ax1, BW[1][5], Cx1);
    }
    __syncthreads();   // once, outside the loop

    #pragma unroll 1
    for (int t = 0; t < T_STEPS; t += 2) {
        RNN_STEP(0, xrB, t + 3)   // step t:   Cx(x_t);   tail preps Cx(x_{t+1})
        RNN_STEP(1, xrA, t + 4)   // step t+1: Cx(x_{t+1}); tail preps Cx(x_{t+2})
    }

    // ---- Epilogue: final h_512 of chain g sits in hbuf[g][0].
    // 2 chains x 16 rows x 10 outs = 320 results.
    if (tid < NCH * BT * O_DIM) {
        const int m32 = tid / O_DIM;          // 0..31 (chain-local row = m32&15)
        const int o   = tid % O_DIM;
        const short* hrow = hbuf[m32 >> 4][0] + (m32 & 15) * PITCH;
        float acc = b_ph[o];
        #pragma unroll 4
        for (int k = 0; k < H_DIM; ++k)
            acc = fmaf(W_ph[o * H_DIM + k], bf2f(hrow[k]), acc);
        out[(size_t)(blockIdx.x * (BT * NCH) + m32) * O_DIM + o] = acc;
    }
}

extern "C" void kernel_launch(void* const* d_in, const int* in_sizes, int n_in,
                              void* d_out, int out_size, void* d_ws, size_t ws_size,
                              hipStream_t stream) {
    const float* x    = (const float*)d_in[0];
    const float* W_hx = (const float*)d_in[1];
    const float* W_hh = (const float*)d_in[2];
    const float* b_hh = (const float*)d_in[3];
    const float* W_ph = (const float*)d_in[4];
    const float* b_ph = (const float*)d_in[5];
    float* out = (float*)d_out;

    rnn_mfma_kernel<<<1024 / (BT * NCH), 512, 0, stream>>>(x, W_hx, W_hh, b_hh, W_ph, b_ph, out);
}